// Round 12
// baseline (135.050 us; speedup 1.0000x reference)
//
#include <hip/hip_runtime.h>
#include <hip/hip_bf16.h>
#include <cmath>

typedef __bf16 bf16;
typedef __attribute__((ext_vector_type(8))) __bf16 bf16x8;
typedef __attribute__((ext_vector_type(4))) __bf16 bf16x4;
typedef __attribute__((ext_vector_type(4))) float f32x4;
typedef __attribute__((ext_vector_type(16))) float f32x16;

#define LOG2E 1.4426950408889634f

// ---------------------------------------------------------------------------
// mask_kernel: madd[b][k] = mask ? -1e9*log2e : 0  (fp32)
// ---------------------------------------------------------------------------
__global__ __launch_bounds__(256)
void mask_kernel(const int* __restrict__ mask, float* __restrict__ madd)
{
    const int gid = blockIdx.x * 256 + threadIdx.x;   // 0..8191
    madd[gid] = mask[gid] ? -1.4426950e9f : 0.f;
}

// ---------------------------------------------------------------------------
// prep_w: transpose + convert 4 weight matrices fp32 [512 k][512 n]
//         -> bf16 WT [512 n][512 k], one per blockIdx.z.
// ---------------------------------------------------------------------------
__global__ __launch_bounds__(256)
void prep_w(const float* __restrict__ w0, const float* __restrict__ w1,
            const float* __restrict__ w2, const float* __restrict__ w3,
            bf16* __restrict__ wt)
{
    const float* W = (blockIdx.z == 0) ? w0 : (blockIdx.z == 1) ? w1
                   : (blockIdx.z == 2) ? w2 : w3;
    bf16* WT = wt + (size_t)blockIdx.z * 512 * 512;

    __shared__ bf16 t[64][72];
    const int k0 = blockIdx.x * 64, n0 = blockIdx.y * 64;
    const int tid = threadIdx.x;
    {
        const int row = tid >> 2;            // k-local
        const int c0 = (tid & 3) * 16;       // n-local
        const float* src = W + (size_t)(k0 + row) * 512 + n0 + c0;
#pragma unroll
        for (int i = 0; i < 16; i += 4) {
            f32x4 f = *(const f32x4*)(src + i);
            t[c0 + i + 0][row] = (bf16)f[0];
            t[c0 + i + 1][row] = (bf16)f[1];
            t[c0 + i + 2][row] = (bf16)f[2];
            t[c0 + i + 3][row] = (bf16)f[3];
        }
    }
    __syncthreads();
    {
        const int nrow = tid >> 2;           // n-local
        const int c0 = (tid & 3) * 16;       // k-local
        bf16* dst = WT + (size_t)(n0 + nrow) * 512 + k0 + c0;
        *(bf16x8*)(dst)     = *(const bf16x8*)&t[nrow][c0];
        *(bf16x8*)(dst + 8) = *(const bf16x8*)&t[nrow][c0 + 8];
    }
}

// ---------------------------------------------------------------------------
// proj_kernel: all three projections in ONE launch (blockIdx.z = 0:q 1:k 2:v).
// Q -> head-split [B,H,S,64] (scaled by 0.125*log2e).
// K -> FRAGMENT layout  kf[bh][T][kstep][kg][hi][c][8]   (head stride 131072)
// V -> FRAGMENT layout  vf[bh][T][kq][vg][hi][c][8]
// ---------------------------------------------------------------------------
__global__ __launch_bounds__(256)
void proj_kernel(const float* __restrict__ qin, const float* __restrict__ kin,
                 const float* __restrict__ vin, const bf16* __restrict__ wt,
                 const float* __restrict__ bq, const float* __restrict__ bk,
                 const float* __restrict__ bv, bf16* __restrict__ qp,
                 bf16* __restrict__ kf, bf16* __restrict__ vf)
{
    const int z = blockIdx.z;
    const float* A    = (z == 0) ? qin : (z == 1) ? kin : vin;
    const bf16* WT    = wt + (size_t)z * 262144;
    const float* bias = (z == 0) ? bq : (z == 1) ? bk : bv;
    const float scale = (z == 0) ? 0.125f * LOG2E : 1.0f;

    const int row0 = blockIdx.x * 64;
    const int col0 = blockIdx.y * 128;
    const int tid = threadIdx.x;
    const int wave = tid >> 6, lane = tid & 63;
    const int wr = wave >> 1, wc = wave & 1;     // wave tile 32 x 64
    const int g = lane >> 4, r = lane & 15;

    __shared__ bf16 As[64][72];
    __shared__ bf16 Bs[128][72];

    const int arow = tid >> 2, ak0 = (tid & 3) * 16;
    const int brow = tid >> 1, bk0 = (tid & 1) * 32;

    f32x4 a0, a1, a2, a3;
    bf16x8 b0, b1, b2, b3;
    {
        const float* asrc = A + (size_t)(row0 + arow) * 512 + ak0;
        a0 = *(const f32x4*)(asrc);     a1 = *(const f32x4*)(asrc + 4);
        a2 = *(const f32x4*)(asrc + 8); a3 = *(const f32x4*)(asrc + 12);
        const bf16* bsrc = WT + (size_t)(col0 + brow) * 512 + bk0;
        b0 = *(const bf16x8*)(bsrc);      b1 = *(const bf16x8*)(bsrc + 8);
        b2 = *(const bf16x8*)(bsrc + 16); b3 = *(const bf16x8*)(bsrc + 24);
    }

    f32x4 acc[2][4] = {};

    for (int kt = 0; kt < 512; kt += 64) {
        {
            bf16x8 v0, v1;
#pragma unroll
            for (int i = 0; i < 4; i++) {
                v0[i] = (bf16)a0[i]; v0[4+i] = (bf16)a1[i];
                v1[i] = (bf16)a2[i]; v1[4+i] = (bf16)a3[i];
            }
            *(bf16x8*)&As[arow][ak0]     = v0;
            *(bf16x8*)&As[arow][ak0 + 8] = v1;
            *(bf16x8*)&Bs[brow][bk0]      = b0;
            *(bf16x8*)&Bs[brow][bk0 +  8] = b1;
            *(bf16x8*)&Bs[brow][bk0 + 16] = b2;
            *(bf16x8*)&Bs[brow][bk0 + 24] = b3;
        }
        __syncthreads();

        if (kt + 64 < 512) {                 // prefetch next K-slab
            const float* asrc = A + (size_t)(row0 + arow) * 512 + kt + 64 + ak0;
            a0 = *(const f32x4*)(asrc);     a1 = *(const f32x4*)(asrc + 4);
            a2 = *(const f32x4*)(asrc + 8); a3 = *(const f32x4*)(asrc + 12);
            const bf16* bsrc = WT + (size_t)(col0 + brow) * 512 + kt + 64 + bk0;
            b0 = *(const bf16x8*)(bsrc);      b1 = *(const bf16x8*)(bsrc + 8);
            b2 = *(const bf16x8*)(bsrc + 16); b3 = *(const bf16x8*)(bsrc + 24);
        }

#pragma unroll
        for (int kk = 0; kk < 64; kk += 32) {
            bf16x8 af[2], bfr[4];
#pragma unroll
            for (int mf = 0; mf < 2; mf++)
                af[mf] = *(const bf16x8*)&As[wr*32 + mf*16 + r][kk + g*8];
#pragma unroll
            for (int nf = 0; nf < 4; nf++)
                bfr[nf] = *(const bf16x8*)&Bs[wc*64 + nf*16 + r][kk + g*8];
#pragma unroll
            for (int mf = 0; mf < 2; mf++)
#pragma unroll
                for (int nf = 0; nf < 4; nf++)
                    acc[mf][nf] = __builtin_amdgcn_mfma_f32_16x16x32_bf16(
                        af[mf], bfr[nf], acc[mf][nf], 0, 0, 0);
        }
        __syncthreads();
    }

#pragma unroll
    for (int mf = 0; mf < 2; mf++) {
#pragma unroll
        for (int nf = 0; nf < 4; nf++) {
            const int rbase = row0 + wr*32 + mf*16 + g*4;
            const int ccol  = col0 + wc*64 + nf*16 + r;
            const float bi = bias[ccol];
            const int h = ccol >> 6, hd = ccol & 63;
            if (z == 0) {
#pragma unroll
                for (int j = 0; j < 4; j++) {
                    const int rrow = rbase + j;
                    const int bb = rrow >> 11, s = rrow & 2047;
                    qp[(((size_t)(bb*8 + h) * 2048) + s) * 64 + hd] =
                        (bf16)((acc[mf][nf][j] + bi) * scale);
                }
            } else if (z == 1) {
                const int kstep = hd >> 4, khi = (hd >> 3) & 1, e = hd & 7;
#pragma unroll
                for (int j = 0; j < 4; j++) {
                    const int rrow = rbase + j;
                    const int bb = rrow >> 11, skey = rrow & 2047;
                    const int T = skey >> 6, kg = (skey >> 5) & 1, cc = skey & 31;
                    kf[(size_t)(bb*8 + h) * 131072 + T*4096 + kstep*1024
                       + kg*512 + khi*256 + cc*8 + e] = (bf16)(acc[mf][nf][j] + bi);
                }
            } else {
                const int vg = hd >> 5, cc = hd & 31;
                const int rrow = rbase;              // j = 0
                const int bb = rrow >> 11, skey = rrow & 2047;
                const int T = skey >> 6, kq = (skey >> 4) & 3;
                const int vhi = (skey >> 3) & 1, e0 = skey & 7;
                bf16x4 pk;
#pragma unroll
                for (int j = 0; j < 4; j++) pk[j] = (bf16)(acc[mf][nf][j] + bi);
                *(bf16x4*)&vf[(size_t)(bb*8 + h) * 131072 + T*4096 + kq*1024
                              + vg*512 + vhi*256 + cc*8 + e0] = pk;
            }
        }
    }
}

// ---------------------------------------------------------------------------
// dense_kernel: final projection, A bf16 [8192,512], out fp32 [8192,512].
// ---------------------------------------------------------------------------
__global__ __launch_bounds__(256)
void dense_kernel(const bf16* __restrict__ ab, const bf16* __restrict__ WT,
                  const float* __restrict__ bias, float* __restrict__ out)
{
    const int row0 = blockIdx.x * 64;
    const int col0 = blockIdx.y * 128;
    const int tid = threadIdx.x;
    const int wave = tid >> 6, lane = tid & 63;
    const int wr = wave >> 1, wc = wave & 1;
    const int g = lane >> 4, r = lane & 15;

    __shared__ bf16 As[64][72];
    __shared__ bf16 Bs[128][72];

    const int arow = tid >> 2, ak0 = (tid & 3) * 16;
    const int brow = tid >> 1, bk0 = (tid & 1) * 32;

    bf16x8 aR0, aR1, b0, b1, b2, b3;
    {
        const bf16* asrc = ab + (size_t)(row0 + arow) * 512 + ak0;
        aR0 = *(const bf16x8*)(asrc); aR1 = *(const bf16x8*)(asrc + 8);
        const bf16* bsrc = WT + (size_t)(col0 + brow) * 512 + bk0;
        b0 = *(const bf16x8*)(bsrc);      b1 = *(const bf16x8*)(bsrc + 8);
        b2 = *(const bf16x8*)(bsrc + 16); b3 = *(const bf16x8*)(bsrc + 24);
    }

    f32x4 acc[2][4] = {};

    for (int kt = 0; kt < 512; kt += 64) {
        *(bf16x8*)&As[arow][ak0]     = aR0;
        *(bf16x8*)&As[arow][ak0 + 8] = aR1;
        *(bf16x8*)&Bs[brow][bk0]      = b0;
        *(bf16x8*)&Bs[brow][bk0 +  8] = b1;
        *(bf16x8*)&Bs[brow][bk0 + 16] = b2;
        *(bf16x8*)&Bs[brow][bk0 + 24] = b3;
        __syncthreads();

        if (kt + 64 < 512) {
            const bf16* asrc = ab + (size_t)(row0 + arow) * 512 + kt + 64 + ak0;
            aR0 = *(const bf16x8*)(asrc); aR1 = *(const bf16x8*)(asrc + 8);
            const bf16* bsrc = WT + (size_t)(col0 + brow) * 512 + kt + 64 + bk0;
            b0 = *(const bf16x8*)(bsrc);      b1 = *(const bf16x8*)(bsrc + 8);
            b2 = *(const bf16x8*)(bsrc + 16); b3 = *(const bf16x8*)(bsrc + 24);
        }

#pragma unroll
        for (int kk = 0; kk < 64; kk += 32) {
            bf16x8 af[2], bfr[4];
#pragma unroll
            for (int mf = 0; mf < 2; mf++)
                af[mf] = *(const bf16x8*)&As[wr*32 + mf*16 + r][kk + g*8];
#pragma unroll
            for (int nf = 0; nf < 4; nf++)
                bfr[nf] = *(const bf16x8*)&Bs[wc*64 + nf*16 + r][kk + g*8];
#pragma unroll
            for (int mf = 0; mf < 2; mf++)
#pragma unroll
                for (int nf = 0; nf < 4; nf++)
                    acc[mf][nf] = __builtin_amdgcn_mfma_f32_16x16x32_bf16(
                        af[mf], bfr[nf], acc[mf][nf], 0, 0, 0);
        }
        __syncthreads();
    }

#pragma unroll
    for (int mf = 0; mf < 2; mf++) {
#pragma unroll
        for (int nf = 0; nf < 4; nf++) {
            const int rbase = row0 + wr*32 + mf*16 + g*4;
            const int ccol  = col0 + wc*64 + nf*16 + r;
            const float bi = bias[ccol];
#pragma unroll
            for (int j = 0; j < 4; j++)
                out[(size_t)(rbase + j) * 512 + ccol] = acc[mf][nf][j] + bi;
        }
    }
}

// ---------------------------------------------------------------------------
// Flash attention: 32x32 MFMA, zero LDS/barriers, fragment-layout K/V,
// SOFTWARE-PIPELINED 2-tile rotation: QK(T+1) MFMAs issue BEFORE softmax(T),
// so the matrix pipe fills while the VALU runs tile T's softmax; PV(T)
// overlaps QK(T+1) latency. kr/vr single-buffered (freed at issue, reloaded
// with a >=2-phase gap). Mask folds into QK accumulator C-init. In-register
// P via cvt_pk + permlane32_swap, fused per-kq to shrink live ranges.
// ---------------------------------------------------------------------------
__global__ __launch_bounds__(256)
void attn_kernel(const bf16* __restrict__ qp, const bf16* __restrict__ kf,
                 const bf16* __restrict__ vf, const float* __restrict__ madd,
                 bf16* __restrict__ attn)
{
    const int i = blockIdx.x;                    // 0..511
    const int swz = (i & 7) * 64 + (i >> 3);     // XCD-contiguous remap
    const int bh = swz >> 4;                     // 0..31
    const int qt = swz & 15;                     // 0..15
    const int b = bh >> 3, h = bh & 7;
    const int tid = threadIdx.x;
    const int w = tid >> 6, lane = tid & 63;
    const int c = lane & 31;                     // query column
    const int hi = lane >> 5;                    // half-wave id

    const bf16* kth = kf + (size_t)(b*8 + h) * 131072;
    const bf16* vth = vf + (size_t)(b*8 + h) * 131072;
    const float* mrow = madd + b * 2048;
    const int loff = hi*256 + c*8;               // lane offset within fragment
    const int q0 = qt * 128;

    // ---- Q fragments (one-time) ----
    bf16x8 qf[4];
    {
        const bf16* qsrc = qp + (size_t)(b*8 + h) * 2048 * 64
                         + (size_t)(q0 + w*32 + c) * 64 + hi*8;
#pragma unroll
        for (int kstep = 0; kstep < 4; kstep++)
            qf[kstep] = *(const bf16x8*)(qsrc + kstep*16);
    }

    float m_run = -INFINITY, l_run = 0.f;
    f32x16 oT0 = {}, oT1 = {};           // O^T: d = dg*32 + 8t + 4hi + j, q = c
    bf16x8 kr[8], vr[8];                 // single-buffered K / V fragments
    f32x16 saA0, saA1, saB0, saB1;       // two score tiles in flight

#define LOADK(t)                                                              \
    {   const bf16* p_ = kth + (t)*4096;                                      \
        _Pragma("unroll")                                                     \
        for (int u = 0; u < 4; u++) {                                         \
            kr[u]   = *(const bf16x8*)(p_ + u*1024 + loff);                   \
            kr[4+u] = *(const bf16x8*)(p_ + u*1024 + 512 + loff);             \
        } }

#define LOADV(t)                                                              \
    {   const bf16* p_ = vth + (t)*4096;                                      \
        _Pragma("unroll")                                                     \
        for (int u = 0; u < 4; u++) {                                         \
            vr[u]   = *(const bf16x8*)(p_ + u*1024 + loff);                   \
            vr[4+u] = *(const bf16x8*)(p_ + u*1024 + 512 + loff);             \
        } }

    // QK: C-init = mask additive, then 8 MFMAs; consumes kr (freed after).
#define QK_ISSUE(t, s0, s1)                                                   \
    {   union { f32x16 v; f32x4 q[4]; } u0_, u1_;                             \
        _Pragma("unroll")                                                     \
        for (int tt = 0; tt < 4; tt++) {                                      \
            u0_.q[tt] = *(const f32x4*)&mrow[(t)*64 +      tt*8 + hi*4];      \
            u1_.q[tt] = *(const f32x4*)&mrow[(t)*64 + 32 + tt*8 + hi*4];      \
        }                                                                     \
        s0 = u0_.v; s1 = u1_.v;                                               \
        __builtin_amdgcn_s_setprio(1);                                        \
        _Pragma("unroll")                                                     \
        for (int ks = 0; ks < 4; ks++) {                                      \
            s0 = __builtin_amdgcn_mfma_f32_32x32x16_bf16(kr[ks],   qf[ks], s0, 0, 0, 0); \
            s1 = __builtin_amdgcn_mfma_f32_32x32x16_bf16(kr[4+ks], qf[ks], s1, 0, 0, 0); \
        }                                                                     \
        __builtin_amdgcn_s_setprio(0);                                        \
    }

    // softmax + PV fused per kq-slice; consumes s0/s1 and vr (freed after).
#define SMPV(s0, s1)                                                          \
    {   f32x4 vm_;                                                            \
        _Pragma("unroll")                                                     \
        for (int j = 0; j < 4; j++)                                           \
            vm_[j] = fmaxf(fmaxf(fmaxf(s0[j], s0[4+j]),                       \
                                 fmaxf(s0[8+j], s0[12+j])),                   \
                           fmaxf(fmaxf(s1[j], s1[4+j]),                       \
                                 fmaxf(s1[8+j], s1[12+j])));                  \
        const float mx_ = fmaxf(fmaxf(vm_[0], vm_[1]), fmaxf(vm_[2], vm_[3]));\
        if (!__all(mx_ <= m_run + 11.54f)) {                                  \
            float mr_ = fmaxf(mx_, __shfl_xor(mx_, 32, 64));                  \
            const float mn_ = fmaxf(m_run, mr_);                              \
            const float corr_ = __builtin_amdgcn_exp2f(m_run - mn_);          \
            oT0 *= corr_; oT1 *= corr_; l_run *= corr_;                       \
            m_run = mn_;                                                      \
        }                                                                     \
        f32x4 ps4_ = {0.f, 0.f, 0.f, 0.f};                                    \
        __builtin_amdgcn_s_setprio(1);                                        \
        _Pragma("unroll")                                                     \
        for (int kg = 0; kg < 2; kg++) {                                      \
            _Pragma("unroll")                                                 \
            for (int ksl = 0; ksl < 2; ksl++) {                               \
                f32x4 e0_, e1_;                                               \
                _Pragma("unroll")                                             \
                for (int j = 0; j < 4; j++) {                                 \
                    e0_[j] = __builtin_amdgcn_exp2f(                          \
                        (kg ? s1[(2*ksl)*4+j]   : s0[(2*ksl)*4+j])   - m_run);\
                    e1_[j] = __builtin_amdgcn_exp2f(                          \
                        (kg ? s1[(2*ksl+1)*4+j] : s0[(2*ksl+1)*4+j]) - m_run);\
                }                                                             \
                unsigned int za0_, za1_, zb0_, zb1_;                          \
                asm("v_cvt_pk_bf16_f32 %0, %1, %2" : "=v"(za0_) : "v"(e0_[0]), "v"(e0_[1])); \
                asm("v_cvt_pk_bf16_f32 %0, %1, %2" : "=v"(za1_) : "v"(e0_[2]), "v"(e0_[3])); \
                asm("v_cvt_pk_bf16_f32 %0, %1, %2" : "=v"(zb0_) : "v"(e1_[0]), "v"(e1_[1])); \
                asm("v_cvt_pk_bf16_f32 %0, %1, %2" : "=v"(zb1_) : "v"(e1_[2]), "v"(e1_[3])); \
                asm volatile("v_permlane32_swap_b32 %0, %1" : "+v"(za0_), "+v"(zb0_)); \
                asm volatile("v_permlane32_swap_b32 %0, %1" : "+v"(za1_), "+v"(zb1_)); \
                union { unsigned int u[4]; bf16x8 v; } pf_;                   \
                pf_.u[0] = za0_; pf_.u[1] = za1_; pf_.u[2] = zb0_; pf_.u[3] = zb1_; \
                const int kq_ = kg*2 + ksl;                                   \
                oT0 = __builtin_amdgcn_mfma_f32_32x32x16_bf16(vr[kq_],   pf_.v, oT0, 0, 0, 0); \
                oT1 = __builtin_amdgcn_mfma_f32_32x32x16_bf16(vr[4+kq_], pf_.v, oT1, 0, 0, 0); \
                ps4_ += e0_ + e1_;                                            \
            }                                                                 \
        }                                                                     \
        __builtin_amdgcn_s_setprio(0);                                        \
        float ps_ = (ps4_[0] + ps4_[1]) + (ps4_[2] + ps4_[3]);                \
        ps_ += __shfl_xor(ps_, 32, 64);                                       \
        l_run += ps_;                                                         \
    }

    // ---- prologue: tiles 0 and 1 ----
    LOADK(0); LOADV(0);
    QK_ISSUE(0, saA0, saA1);
    LOADK(1);

    // ---- pipelined main loop: tiles T (A) and T+1 (B) per iteration ----
    for (int T = 0; T < 32; T += 2) {
        QK_ISSUE(T+1, saB0, saB1);           // MFMA: scores(T+1), frees kr
        if (T + 2 < 32) LOADK(T+2);          // VMEM into freed kr
        SMPV(saA0, saA1);                    // VALU+MFMA: tile T, frees vr
        LOADV(T+1);                          // VMEM into freed vr
        if (T + 2 < 32) {
            QK_ISSUE(T+2, saA0, saA1);       // MFMA: scores(T+2), frees kr
            LOADK(T+3);                      // T<=28 here, so T+3<=31
        }
        SMPV(saB0, saB1);                    // tile T+1, frees vr
        if (T + 2 < 32) LOADV(T+2);
    }

#undef LOADK
#undef LOADV
#undef QK_ISSUE
#undef SMPV

    // ---- epilogue: O^T lane-local per query; normalize & store ----
    const float inv = 1.0f / l_run;
    const int s = q0 + w*32 + c;
    bf16* dst = attn + ((size_t)(b*2048) + s) * 512 + h*64;
#pragma unroll
    for (int t = 0; t < 4; t++) {
        bf16x4 o0, o1;
#pragma unroll
        for (int j = 0; j < 4; j++) {
            o0[j] = (bf16)(oT0[t*4+j] * inv);
            o1[j] = (bf16)(oT1[t*4+j] * inv);
        }
        *(bf16x4*)(dst +      t*8 + hi*4) = o0;
        *(bf16x4*)(dst + 32 + t*8 + hi*4) = o1;
    }
}

// ---------------------------------------------------------------------------
extern "C" void kernel_launch(void* const* d_in, const int* in_sizes, int n_in,
                              void* d_out, int out_size, void* d_ws, size_t ws_size,
                              hipStream_t stream)
{
    const float* q    = (const float*)d_in[0];
    const float* k    = (const float*)d_in[1];
    const float* v    = (const float*)d_in[2];
    const int*   mask = (const int*)  d_in[3];
    const float* wq   = (const float*)d_in[4];
    const float* bq   = (const float*)d_in[5];
    const float* wk   = (const float*)d_in[6];
    const float* bk   = (const float*)d_in[7];
    const float* wv   = (const float*)d_in[8];
    const float* bv   = (const float*)d_in[9];
    const float* wd   = (const float*)d_in[10];
    const float* bd   = (const float*)d_in[11];
    float* out = (float*)d_out;

    const size_t NELEM = (size_t)4 * 2048 * 512;   // 4,194,304
    bf16* qp  = (bf16*)d_ws;
    bf16* kfr = qp + NELEM;                         // K fragment layout
    bf16* vfr = kfr + NELEM;                        // V fragment layout
    bf16* ab  = vfr + NELEM;                        // merged attn output
    bf16* wt  = ab + NELEM;                         // 4 x 512x512 bf16
    float* madd = (float*)(wt + 4 * 262144);        // 4 x 2048 fp32

    mask_kernel<<<dim3(32), dim3(256), 0, stream>>>(mask, madd);

    prep_w<<<dim3(8, 8, 4), dim3(256), 0, stream>>>(wq, wk, wv, wd, wt);

    proj_kernel<<<dim3(128, 4, 3), dim3(256), 0, stream>>>(
        q, k, v, wt, bq, bk, bv, qp, kfr, vfr);

    attn_kernel<<<dim3(512), dim3(256), 0, stream>>>(qp, kfr, vfr, madd, ab);

    dense_kernel<<<dim3(128, 4), dim3(256), 0, stream>>>(
        ab, wt + 3*262144, bd, out);
}

// Round 13
// 108.659 us; speedup vs baseline: 1.2429x; 1.2429x over previous
//
#include <hip/hip_runtime.h>
#include <hip/hip_bf16.h>
#include <cmath>

typedef __bf16 bf16;
typedef __attribute__((ext_vector_type(8))) __bf16 bf16x8;
typedef __attribute__((ext_vector_type(4))) __bf16 bf16x4;
typedef __attribute__((ext_vector_type(4))) float f32x4;
typedef __attribute__((ext_vector_type(16))) float f32x16;

#define LOG2E 1.4426950408889634f

// ---------------------------------------------------------------------------
// prep_w: transpose + convert 4 weight matrices fp32 [512 k][512 n]
//         -> bf16 WT [512 n][512 k], one per blockIdx.z.
// ---------------------------------------------------------------------------
__global__ __launch_bounds__(256)
void prep_w(const float* __restrict__ w0, const float* __restrict__ w1,
            const float* __restrict__ w2, const float* __restrict__ w3,
            bf16* __restrict__ wt)
{
    const float* W = (blockIdx.z == 0) ? w0 : (blockIdx.z == 1) ? w1
                   : (blockIdx.z == 2) ? w2 : w3;
    bf16* WT = wt + (size_t)blockIdx.z * 512 * 512;

    __shared__ bf16 t[64][72];
    const int k0 = blockIdx.x * 64, n0 = blockIdx.y * 64;
    const int tid = threadIdx.x;
    {
        const int row = tid >> 2;            // k-local
        const int c0 = (tid & 3) * 16;       // n-local
        const float* src = W + (size_t)(k0 + row) * 512 + n0 + c0;
#pragma unroll
        for (int i = 0; i < 16; i += 4) {
            f32x4 f = *(const f32x4*)(src + i);
            t[c0 + i + 0][row] = (bf16)f[0];
            t[c0 + i + 1][row] = (bf16)f[1];
            t[c0 + i + 2][row] = (bf16)f[2];
            t[c0 + i + 3][row] = (bf16)f[3];
        }
    }
    __syncthreads();
    {
        const int nrow = tid >> 2;           // n-local
        const int c0 = (tid & 3) * 16;       // k-local
        bf16* dst = WT + (size_t)(n0 + nrow) * 512 + k0 + c0;
        *(bf16x8*)(dst)     = *(const bf16x8*)&t[nrow][c0];
        *(bf16x8*)(dst + 8) = *(const bf16x8*)&t[nrow][c0 + 8];
    }
}

// ---------------------------------------------------------------------------
// proj_kernel: all three projections in ONE launch (blockIdx.z = 0:q 1:k 2:v).
// Tile 64x128, BK=64, 4 waves (2x2, each 32x64). Grid (128, 4, 3).
// ---------------------------------------------------------------------------
__global__ __launch_bounds__(256)
void proj_kernel(const float* __restrict__ qin, const float* __restrict__ kin,
                 const float* __restrict__ vin, const bf16* __restrict__ wt,
                 const float* __restrict__ bq, const float* __restrict__ bk,
                 const float* __restrict__ bv, bf16* __restrict__ qp,
                 bf16* __restrict__ kp, bf16* __restrict__ vpT)
{
    const int z = blockIdx.z;
    const float* A    = (z == 0) ? qin : (z == 1) ? kin : vin;
    const bf16* WT    = wt + (size_t)z * 262144;
    const float* bias = (z == 0) ? bq : (z == 1) ? bk : bv;
    const float scale = (z == 0) ? 0.125f * LOG2E : 1.0f;

    const int row0 = blockIdx.x * 64;
    const int col0 = blockIdx.y * 128;
    const int tid = threadIdx.x;
    const int wave = tid >> 6, lane = tid & 63;
    const int wr = wave >> 1, wc = wave & 1;     // wave tile 32 x 64
    const int g = lane >> 4, r = lane & 15;

    __shared__ bf16 As[64][72];
    __shared__ bf16 Bs[128][72];

    const int arow = tid >> 2, ak0 = (tid & 3) * 16;
    const int brow = tid >> 1, bk0 = (tid & 1) * 32;

    f32x4 a0, a1, a2, a3;
    bf16x8 b0, b1, b2, b3;
    {
        const float* asrc = A + (size_t)(row0 + arow) * 512 + ak0;
        a0 = *(const f32x4*)(asrc);     a1 = *(const f32x4*)(asrc + 4);
        a2 = *(const f32x4*)(asrc + 8); a3 = *(const f32x4*)(asrc + 12);
        const bf16* bsrc = WT + (size_t)(col0 + brow) * 512 + bk0;
        b0 = *(const bf16x8*)(bsrc);      b1 = *(const bf16x8*)(bsrc + 8);
        b2 = *(const bf16x8*)(bsrc + 16); b3 = *(const bf16x8*)(bsrc + 24);
    }

    f32x4 acc[2][4] = {};

    for (int kt = 0; kt < 512; kt += 64) {
        {
            bf16x8 v0, v1;
#pragma unroll
            for (int i = 0; i < 4; i++) {
                v0[i] = (bf16)a0[i]; v0[4+i] = (bf16)a1[i];
                v1[i] = (bf16)a2[i]; v1[4+i] = (bf16)a3[i];
            }
            *(bf16x8*)&As[arow][ak0]     = v0;
            *(bf16x8*)&As[arow][ak0 + 8] = v1;
            *(bf16x8*)&Bs[brow][bk0]      = b0;
            *(bf16x8*)&Bs[brow][bk0 +  8] = b1;
            *(bf16x8*)&Bs[brow][bk0 + 16] = b2;
            *(bf16x8*)&Bs[brow][bk0 + 24] = b3;
        }
        __syncthreads();

        if (kt + 64 < 512) {                 // prefetch next K-slab
            const float* asrc = A + (size_t)(row0 + arow) * 512 + kt + 64 + ak0;
            a0 = *(const f32x4*)(asrc);     a1 = *(const f32x4*)(asrc + 4);
            a2 = *(const f32x4*)(asrc + 8); a3 = *(const f32x4*)(asrc + 12);
            const bf16* bsrc = WT + (size_t)(col0 + brow) * 512 + kt + 64 + bk0;
            b0 = *(const bf16x8*)(bsrc);      b1 = *(const bf16x8*)(bsrc + 8);
            b2 = *(const bf16x8*)(bsrc + 16); b3 = *(const bf16x8*)(bsrc + 24);
        }

#pragma unroll
        for (int kk = 0; kk < 64; kk += 32) {
            bf16x8 af[2], bfr[4];
#pragma unroll
            for (int mf = 0; mf < 2; mf++)
                af[mf] = *(const bf16x8*)&As[wr*32 + mf*16 + r][kk + g*8];
#pragma unroll
            for (int nf = 0; nf < 4; nf++)
                bfr[nf] = *(const bf16x8*)&Bs[wc*64 + nf*16 + r][kk + g*8];
#pragma unroll
            for (int mf = 0; mf < 2; mf++)
#pragma unroll
                for (int nf = 0; nf < 4; nf++)
                    acc[mf][nf] = __builtin_amdgcn_mfma_f32_16x16x32_bf16(
                        af[mf], bfr[nf], acc[mf][nf], 0, 0, 0);
        }
        __syncthreads();
    }

#pragma unroll
    for (int mf = 0; mf < 2; mf++) {
#pragma unroll
        for (int nf = 0; nf < 4; nf++) {
            const int rbase = row0 + wr*32 + mf*16 + g*4;
            const int ccol  = col0 + wc*64 + nf*16 + r;
            const float bi = bias[ccol];
            const int h = ccol >> 6, hd = ccol & 63;
            if (z < 2) {
                bf16* C = (z == 0) ? qp : kp;
#pragma unroll
                for (int j = 0; j < 4; j++) {
                    const int rrow = rbase + j;
                    const int b = rrow >> 11, s = rrow & 2047;
                    C[(((size_t)(b*8 + h) * 2048) + s) * 64 + hd] =
                        (bf16)((acc[mf][nf][j] + bi) * scale);
                }
            } else {
                const int b = rbase >> 11, s = rbase & 2047;
                bf16x4 pk;
#pragma unroll
                for (int j = 0; j < 4; j++) pk[j] = (bf16)(acc[mf][nf][j] + bi);
                *(bf16x4*)(vpT + ((size_t)(b*8 + h) * 64 + hd) * 2048 + s) = pk;
            }
        }
    }
}

// ---------------------------------------------------------------------------
// dense_kernel: final projection, A bf16 [8192,512], out fp32 [8192,512].
// ---------------------------------------------------------------------------
__global__ __launch_bounds__(256)
void dense_kernel(const bf16* __restrict__ ab, const bf16* __restrict__ WT,
                  const float* __restrict__ bias, float* __restrict__ out)
{
    const int row0 = blockIdx.x * 64;
    const int col0 = blockIdx.y * 128;
    const int tid = threadIdx.x;
    const int wave = tid >> 6, lane = tid & 63;
    const int wr = wave >> 1, wc = wave & 1;
    const int g = lane >> 4, r = lane & 15;

    __shared__ bf16 As[64][72];
    __shared__ bf16 Bs[128][72];

    const int arow = tid >> 2, ak0 = (tid & 3) * 16;
    const int brow = tid >> 1, bk0 = (tid & 1) * 32;

    bf16x8 aR0, aR1, b0, b1, b2, b3;
    {
        const bf16* asrc = ab + (size_t)(row0 + arow) * 512 + ak0;
        aR0 = *(const bf16x8*)(asrc); aR1 = *(const bf16x8*)(asrc + 8);
        const bf16* bsrc = WT + (size_t)(col0 + brow) * 512 + bk0;
        b0 = *(const bf16x8*)(bsrc);      b1 = *(const bf16x8*)(bsrc + 8);
        b2 = *(const bf16x8*)(bsrc + 16); b3 = *(const bf16x8*)(bsrc + 24);
    }

    f32x4 acc[2][4] = {};

    for (int kt = 0; kt < 512; kt += 64) {
        *(bf16x8*)&As[arow][ak0]     = aR0;
        *(bf16x8*)&As[arow][ak0 + 8] = aR1;
        *(bf16x8*)&Bs[brow][bk0]      = b0;
        *(bf16x8*)&Bs[brow][bk0 +  8] = b1;
        *(bf16x8*)&Bs[brow][bk0 + 16] = b2;
        *(bf16x8*)&Bs[brow][bk0 + 24] = b3;
        __syncthreads();

        if (kt + 64 < 512) {
            const bf16* asrc = ab + (size_t)(row0 + arow) * 512 + kt + 64 + ak0;
            aR0 = *(const bf16x8*)(asrc); aR1 = *(const bf16x8*)(asrc + 8);
            const bf16* bsrc = WT + (size_t)(col0 + brow) * 512 + kt + 64 + bk0;
            b0 = *(const bf16x8*)(bsrc);      b1 = *(const bf16x8*)(bsrc + 8);
            b2 = *(const bf16x8*)(bsrc + 16); b3 = *(const bf16x8*)(bsrc + 24);
        }

#pragma unroll
        for (int kk = 0; kk < 64; kk += 32) {
            bf16x8 af[2], bfr[4];
#pragma unroll
            for (int mf = 0; mf < 2; mf++)
                af[mf] = *(const bf16x8*)&As[wr*32 + mf*16 + r][kk + g*8];
#pragma unroll
            for (int nf = 0; nf < 4; nf++)
                bfr[nf] = *(const bf16x8*)&Bs[wc*64 + nf*16 + r][kk + g*8];
#pragma unroll
            for (int mf = 0; mf < 2; mf++)
#pragma unroll
                for (int nf = 0; nf < 4; nf++)
                    acc[mf][nf] = __builtin_amdgcn_mfma_f32_16x16x32_bf16(
                        af[mf], bfr[nf], acc[mf][nf], 0, 0, 0);
        }
        __syncthreads();
    }

#pragma unroll
    for (int mf = 0; mf < 2; mf++) {
#pragma unroll
        for (int nf = 0; nf < 4; nf++) {
            const int rbase = row0 + wr*32 + mf*16 + g*4;
            const int ccol  = col0 + wc*64 + nf*16 + r;
            const float bi = bias[ccol];
#pragma unroll
            for (int j = 0; j < 4; j++)
                out[(size_t)(rbase + j) * 512 + ccol] = acc[mf][nf][j] + bi;
        }
    }
}

// ---------------------------------------------------------------------------
// Flash attention (round-6 optimum + 2 isolated VALU cuts):
// 32x32 MFMA, in-register P via cvt_pk + permlane32_swap, K/V double-buffered
// LDS, one barrier per tile, lazy defer-max.
// NEW (1): mask additive loads directly into the QK accumulator C-init
//          (deletes 32 v_add + 32 zero-init per tile per wave).
// NEW (2): l_run stays a per-lane HALF-sum; the cross-half shuffle runs ONCE
//          in the epilogue (m_run/corr are per-query uniform across hi).
// ---------------------------------------------------------------------------
__global__ __launch_bounds__(256)
void attn_kernel(const bf16* __restrict__ qp, const bf16* __restrict__ kp,
                 const bf16* __restrict__ vpT, const int* __restrict__ mask,
                 bf16* __restrict__ attn)
{
    const int bh = blockIdx.x;           // 0..31
    const int qt = blockIdx.y;           // 0..15
    const int b = bh >> 3, h = bh & 7;
    const int tid = threadIdx.x;
    const int w = tid >> 6, lane = tid & 63;
    const int c = lane & 31;             // query column
    const int hi = lane >> 5;            // half-wave id

    __shared__ bf16 Ks[2][64][72];               // [buf][key][hd]
    __shared__ bf16 Vt[2][64][72];               // [buf][hd][key]
    __shared__ __align__(16) float madd2[2048];  // mask * -1e9*log2e

    const size_t head_base = (size_t)(b*8 + h) * 2048 * 64;
    const int q0 = qt * 128;
    const bf16* kbase = kp  + head_base;
    const bf16* vbase = vpT + head_base;

    // ---- stage mask additive (whole row, once) ----
    {
        const int4* m4 = (const int4*)(mask + b * 2048);
#pragma unroll
        for (int i = 0; i < 2; i++) {
            const int4 mv = m4[tid*2 + i];
            f32x4 f;
            f[0] = mv.x ? -1.4426950e9f : 0.f;
            f[1] = mv.y ? -1.4426950e9f : 0.f;
            f[2] = mv.z ? -1.4426950e9f : 0.f;
            f[3] = mv.w ? -1.4426950e9f : 0.f;
            *(f32x4*)&madd2[tid*8 + i*4] = f;
        }
    }

    // ---- Q fragments direct from global: B[k=hd][col=q] ----
    bf16x8 qf[4];
    {
        const bf16* qsrc = qp + head_base + (size_t)(q0 + w*32 + c) * 64 + hi*8;
#pragma unroll
        for (int kstep = 0; kstep < 4; kstep++)
            qf[kstep] = *(const bf16x8*)(qsrc + kstep*16);
    }

    // ---- staging lane mapping + preload tile 0 into buf 0 ----
    const int srow = tid >> 2;
    const int sc0  = (tid & 3) * 16;
    bf16x8 kr0, kr1, vr0, vr1;
    kr0 = *(const bf16x8*)(kbase + (size_t)srow * 64 + sc0);
    kr1 = *(const bf16x8*)(kbase + (size_t)srow * 64 + sc0 + 8);
    vr0 = *(const bf16x8*)(vbase + (size_t)srow * 2048 + sc0);
    vr1 = *(const bf16x8*)(vbase + (size_t)srow * 2048 + sc0 + 8);
    *(bf16x8*)&Ks[0][srow][sc0]     = kr0;
    *(bf16x8*)&Ks[0][srow][sc0 + 8] = kr1;
    *(bf16x8*)&Vt[0][srow][sc0]     = vr0;
    *(bf16x8*)&Vt[0][srow][sc0 + 8] = vr1;

    float m_run = -INFINITY, l_half = 0.f;       // l: per-lane HALF sum
    f32x16 oT0 = {}, oT1 = {};           // O^T: d = dg*32 + 8t + 4hi + j, q = c

    union f16x4q { f32x16 v; f32x4 q[4]; };

    int it = 0;
    for (int kt = 0; kt < 2048; kt += 64, it ^= 1) {
        __syncthreads();                 // buf[it] ready for all
        const bool more = (kt + 64) < 2048;
        if (more) {
            kr0 = *(const bf16x8*)(kbase + (size_t)(kt+64+srow)*64 + sc0);
            kr1 = *(const bf16x8*)(kbase + (size_t)(kt+64+srow)*64 + sc0 + 8);
            vr0 = *(const bf16x8*)(vbase + (size_t)srow*2048 + kt+64 + sc0);
            vr1 = *(const bf16x8*)(vbase + (size_t)srow*2048 + kt+64 + sc0 + 8);
        }

        // ---- accumulator C-INIT = mask additive (replaces zero-init + add) ----
        f16x4q sa0, sa1;
#pragma unroll
        for (int t = 0; t < 4; t++) {
            sa0.q[t] = *(const f32x4*)&madd2[kt +      t*8 + hi*4];
            sa1.q[t] = *(const f32x4*)&madd2[kt + 32 + t*8 + hi*4];
        }

        // ---- S^T = K * Q^T + madd (two 32-key groups) ----
        __builtin_amdgcn_s_setprio(1);
#pragma unroll
        for (int kstep = 0; kstep < 4; kstep++) {
            const bf16x8 k0 = *(const bf16x8*)&Ks[it][c][kstep*16 + hi*8];
            const bf16x8 k1 = *(const bf16x8*)&Ks[it][32 + c][kstep*16 + hi*8];
            sa0.v = __builtin_amdgcn_mfma_f32_32x32x16_bf16(k0, qf[kstep], sa0.v, 0, 0, 0);
            sa1.v = __builtin_amdgcn_mfma_f32_32x32x16_bf16(k1, qf[kstep], sa1.v, 0, 0, 0);
        }
        __builtin_amdgcn_s_setprio(0);

        // ---- in-lane max over masked scores (nested triples -> v_max3) ----
        f32x4 vm;
#pragma unroll
        for (int j = 0; j < 4; j++)
            vm[j] = fmaxf(fmaxf(fmaxf(sa0.v[j], sa0.v[4+j]),
                                fmaxf(sa0.v[8+j], sa0.v[12+j])),
                          fmaxf(fmaxf(sa1.v[j], sa1.v[4+j]),
                                fmaxf(sa1.v[8+j], sa1.v[12+j])));
        const float mx = fmaxf(fmaxf(vm[0], vm[1]), fmaxf(vm[2], vm[3]));

        // lazy defer-max: vote on local max; full reduce only on trigger
        if (!__all(mx <= m_run + 11.54f)) {
            float mr = fmaxf(mx, __shfl_xor(mx, 32, 64));
            const float mn = fmaxf(m_run, mr);
            const float corr = __builtin_amdgcn_exp2f(m_run - mn);
            oT0 *= corr; oT1 *= corr; l_half *= corr;
            m_run = mn;
        }

        // ---- exp2 + pack to bf16 pairs (quadrant regs); psum packed ----
        f32x4 ps4 = {0.f, 0.f, 0.f, 0.f};
        unsigned int z[2][4][2];
#pragma unroll
        for (int t = 0; t < 4; t++) {
            f32x4 e0, e1;
#pragma unroll
            for (int j = 0; j < 4; j++) {
                e0[j] = __builtin_amdgcn_exp2f(sa0.v[t*4+j] - m_run);
                e1[j] = __builtin_amdgcn_exp2f(sa1.v[t*4+j] - m_run);
            }
            asm("v_cvt_pk_bf16_f32 %0, %1, %2" : "=v"(z[0][t][0]) : "v"(e0[0]), "v"(e0[1]));
            asm("v_cvt_pk_bf16_f32 %0, %1, %2" : "=v"(z[0][t][1]) : "v"(e0[2]), "v"(e0[3]));
            asm("v_cvt_pk_bf16_f32 %0, %1, %2" : "=v"(z[1][t][0]) : "v"(e1[0]), "v"(e1[1]));
            asm("v_cvt_pk_bf16_f32 %0, %1, %2" : "=v"(z[1][t][1]) : "v"(e1[2]), "v"(e1[3]));
            ps4 += e0 + e1;
        }
        l_half += (ps4[0] + ps4[1]) + (ps4[2] + ps4[3]);   // no shuffle here

        // ---- O^T += V^T * P^T  (P^T B-frags via permlane32_swap) ----
        __builtin_amdgcn_s_setprio(1);
#pragma unroll
        for (int kg = 0; kg < 2; kg++) {
#pragma unroll
            for (int ksl = 0; ksl < 2; ksl++) {
                unsigned int a0 = z[kg][2*ksl][0], a1 = z[kg][2*ksl][1];
                unsigned int b0 = z[kg][2*ksl+1][0], b1 = z[kg][2*ksl+1][1];
                asm volatile("v_permlane32_swap_b32 %0, %1" : "+v"(a0), "+v"(b0));
                asm volatile("v_permlane32_swap_b32 %0, %1" : "+v"(a1), "+v"(b1));
                union { unsigned int u[4]; bf16x8 v; } pf;
                pf.u[0] = a0; pf.u[1] = a1; pf.u[2] = b0; pf.u[3] = b1;
                const int kcol = (kg*2 + ksl)*16 + hi*8;
                const bf16x8 v0 = *(const bf16x8*)&Vt[it][c][kcol];
                const bf16x8 v1 = *(const bf16x8*)&Vt[it][32 + c][kcol];
                oT0 = __builtin_amdgcn_mfma_f32_32x32x16_bf16(v0, pf.v, oT0, 0, 0, 0);
                oT1 = __builtin_amdgcn_mfma_f32_32x32x16_bf16(v1, pf.v, oT1, 0, 0, 0);
            }
        }
        __builtin_amdgcn_s_setprio(0);

        // ---- write prefetched tile into the other buffer ----
        if (more) {
            *(bf16x8*)&Ks[it^1][srow][sc0]     = kr0;
            *(bf16x8*)&Ks[it^1][srow][sc0 + 8] = kr1;
            *(bf16x8*)&Vt[it^1][srow][sc0]     = vr0;
            *(bf16x8*)&Vt[it^1][srow][sc0 + 8] = vr1;
        }
    }

    // ---- epilogue: combine half-sums once, normalize & store ----
    const float l_run = l_half + __shfl_xor(l_half, 32, 64);
    const float inv = 1.0f / l_run;
    const int s = q0 + w*32 + c;
    bf16* dst = attn + ((size_t)(b*2048) + s) * 512 + h*64;
#pragma unroll
    for (int t = 0; t < 4; t++) {
        bf16x4 o0, o1;
#pragma unroll
        for (int j = 0; j < 4; j++) {
            o0[j] = (bf16)(oT0[t*4+j] * inv);
            o1[j] = (bf16)(oT1[t*4+j] * inv);
        }
        *(bf16x4*)(dst +      t*8 + hi*4) = o0;
        *(bf16x4*)(dst + 32 + t*8 + hi*4) = o1;
    }
}

// ---------------------------------------------------------------------------
extern "C" void kernel_launch(void* const* d_in, const int* in_sizes, int n_in,
                              void* d_out, int out_size, void* d_ws, size_t ws_size,
                              hipStream_t stream)
{
    const float* q    = (const float*)d_in[0];
    const float* k    = (const float*)d_in[1];
    const float* v    = (const float*)d_in[2];
    const int*   mask = (const int*)  d_in[3];
    const float* wq   = (const float*)d_in[4];
    const float* bq   = (const float*)d_in[5];
    const float* wk   = (const float*)d_in[6];
    const float* bk   = (const float*)d_in[7];
    const float* wv   = (const float*)d_in[8];
    const float* bv   = (const float*)d_in[9];
    const float* wd   = (const float*)d_in[10];
    const float* bd   = (const float*)d_in[11];
    float* out = (float*)d_out;

    const size_t NELEM = (size_t)4 * 2048 * 512;   // 4,194,304
    bf16* qp  = (bf16*)d_ws;
    bf16* kp  = qp + NELEM;
    bf16* vpT = kp + NELEM;                         // [B,H,64,S]
    bf16* ab  = vpT + NELEM;                        // merged attn output
    bf16* wt  = ab + NELEM;                         // 4 x 512x512 bf16

    prep_w<<<dim3(8, 8, 4), dim3(256), 0, stream>>>(wq, wk, wv, wd, wt);

    proj_kernel<<<dim3(128, 4, 3), dim3(256), 0, stream>>>(
        q, k, v, wt, bq, bk, bv, qp, kp, vpT);

    attn_kernel<<<dim3(32, 16), dim3(256), 0, stream>>>(qp, kp, vpT, mask, ab);

    dense_kernel<<<dim3(128, 4), dim3(256), 0, stream>>>(
        ab, wt + 3*262144, bd, out);
}